// Round 2
// baseline (627.007 us; speedup 1.0000x reference)
//
#include <hip/hip_runtime.h>

using u32 = unsigned int;
typedef int v4i __attribute__((ext_vector_type(4)));

// ===== geometry =====
constexpr int N_IMG   = 16;
constexpr int PADROW  = 4096;   // 64 px * 64 ch bytes
constexpr int ROWS_PI = 58;     // 56 real + top/bottom pad
constexpr int NB      = 512;    // cooperative grid: 2 blocks/CU, runtime-validated co-residency

// ===== workspace layout (bytes) =====
constexpr size_t OFS_QX   = 4096;
constexpr size_t SZ_QPAD  = (size_t)(1 + N_IMG * ROWS_PI) * PADROW;
constexpr size_t OFS_Q1   = OFS_QX + SZ_QPAD;
constexpr size_t OFS_O1   = OFS_Q1 + SZ_QPAD;
constexpr size_t SZ_OF    = (size_t)N_IMG * 56 * 56 * 64 * 4;
constexpr size_t OFS_O2   = OFS_O1 + SZ_OF;
constexpr size_t OFS_QW1  = OFS_O2 + SZ_OF;
constexpr size_t OFS_QW2  = OFS_QW1 + 36864;
constexpr size_t OFS_WB1  = OFS_QW2 + 36864;
constexpr size_t OFS_WB2  = OFS_WB1 + 18432;
constexpr size_t OFS_WSUM = OFS_WB2 + 18432;      // 64 ints (zeroed)
constexpr size_t OFS_SCAL = OFS_WSUM + 256;       // rmax1 @+128, rmax2 @+256 — own cachelines (zeroed)
constexpr size_t OFS_BAR  = OFS_SCAL + 384;       // 16 u32 grid-barrier counters (zeroed)
constexpr size_t OFS_STX  = OFS_BAR + 64;         // 4608 ints (zeroed)
constexpr size_t OFS_STQ  = OFS_STX + 18432;      // 4608 ints (zeroed)
constexpr size_t OFS_WSRED= OFS_STQ + 18432;      // 512 floats absmax partials (written, not zeroed)
constexpr size_t WS_NEED  = OFS_WSRED + 2048;
constexpr size_t ZSPAN    = OFS_WSRED - OFS_WSUM; // one memset covers wsum+scal+bar+stx+stq
constexpr size_t OUTN     = (size_t)16 * 64 * 56 * 56;

// ===== shared memory union (max 52384 B -> 2 blocks/CU with margin) =====
union __align__(16) SMem {
    struct { u32 lb[11520]; u32 lin[1320]; float red[256]; } conv; // 46080+5280+1024
    struct { char lq[4096]; } qx;
    struct { u32 red[2048]; } st;
    struct { float lt[64 * 57]; } fin;
    struct { float red[256]; } amax;
    struct { int wsl[256]; } qw;
    struct { long long r1[256]; } hm;
};
static_assert(sizeof(SMem) <= 64 * 1024, "LDS budget");

// ===== helpers =====
static __device__ __forceinline__ int aload(const int* p) {
    return __hip_atomic_load((int*)p, __ATOMIC_RELAXED, __HIP_MEMORY_SCOPE_AGENT);
}
static __device__ __forceinline__ u32 aloadu(u32* p) {
    return __hip_atomic_load(p, __ATOMIC_RELAXED, __HIP_MEMORY_SCOPE_AGENT);
}

// device-scope grid barrier; counters pre-zeroed by hipMemsetAsync each launch.
// Cooperative launch guarantees co-residency; guard is a short failsafe only.
static __device__ __forceinline__ void gsync(u32* bar, int idx) {
    __syncthreads();
    if (threadIdx.x == 0) {
        __threadfence();
        __hip_atomic_fetch_add(&bar[idx], 1u, __ATOMIC_ACQ_REL, __HIP_MEMORY_SCOPE_AGENT);
        int guard = 0;
        while (__hip_atomic_load(&bar[idx], __ATOMIC_ACQUIRE, __HIP_MEMORY_SCOPE_AGENT) < (u32)NB) {
            __builtin_amdgcn_s_sleep(2);
            if (++guard > (1 << 20)) break;   // ~0.1s failsafe; never expected to trip
        }
        __threadfence();
    }
    __syncthreads();
}

static __device__ __forceinline__ float block_redmax(float v, float* red, int t) {
    red[t] = v; __syncthreads();
    for (int s = 128; s > 0; s >>= 1) {
        if (t < s) red[t] = fmaxf(red[t], red[t + s]);
        __syncthreads();
    }
    float r = red[0]; __syncthreads();
    return r;
}

// ===== bit-stats (identical math to the verified multi-kernel k_stats) =====
static __device__ __forceinline__ void unpack_acc(u32 v, u32 pk[8]) {
#pragma unroll
    for (int k = 0; k < 8; k++) pk[k] += (v >> k) & 0x01010101u;
}

static __device__ __forceinline__ void reduce_cat(u32* red, int* gdst, const u32 pk[8],
                                                  bool active, int t) {
#pragma unroll
    for (int k = 0; k < 8; k++) red[k * 256 + t] = active ? pk[k] : 0u;
    __syncthreads();
#pragma unroll
    for (int p = t; p < 512; p += 256) {
        int ci = p >> 3, k = p & 7, ci4 = ci >> 2, b = ci & 3;
        int sum = 0;
#pragma unroll
        for (int xo = 0; xo < 16; xo++)
            sum += (red[k * 256 + xo * 16 + ci4] >> (8 * b)) & 0xFF;
        if (sum) atomicAdd(&gdst[p], sum);
    }
    __syncthreads();
}

static __device__ void stats_unit(SMem* sm, const char* qpad, u32 xorm, int* gst, int s, int t) {
    __syncthreads();                      // LDS handoff from conv
    int n = s / 14, slab = s - n * 14;
    int ci4 = t & 15, xo = t >> 4;
    const u32* img = (const u32*)(qpad + (size_t)(2 + n * ROWS_PI) * PADROW);
    u32 xm = xorm * 0x01010101u;
    u32* red = sm->st.red;
    int y0 = slab * 4;
    {   // main total (j=0)
        u32 pk[8] = {0,0,0,0,0,0,0,0};
#pragma unroll
        for (int r = 0; r < 4; r++) {
            const u32* row = img + (size_t)(y0 + r) * 1024;
#pragma unroll
            for (int j = 0; j < 4; j++) {
                int xx = xo + 16 * j;
                if (xx < 56) unpack_acc(row[xx * 16 + ci4] ^ xm, pk);
            }
        }
        reduce_cat(red, gst + 0 * 512, pk, true, t);
    }
    {   // Cleft (j=3)
        u32 pk[8] = {0,0,0,0,0,0,0,0};
        bool act = (xo == 0);
        if (act)
#pragma unroll
            for (int r = 0; r < 4; r++)
                unpack_acc(img[(size_t)(y0 + r) * 1024 + ci4] ^ xm, pk);
        reduce_cat(red, gst + 3 * 512, pk, act, t);
    }
    {   // Cright (j=4)
        u32 pk[8] = {0,0,0,0,0,0,0,0};
        bool act = (xo == 7);
        if (act)
#pragma unroll
            for (int r = 0; r < 4; r++)
                unpack_acc(img[(size_t)(y0 + r) * 1024 + 55 * 16 + ci4] ^ xm, pk);
        reduce_cat(red, gst + 4 * 512, pk, act, t);
    }
    if (slab == 0) {   // Rtop (j=1) + corners 5,6
        u32 pk[8] = {0,0,0,0,0,0,0,0};
#pragma unroll
        for (int j = 0; j < 4; j++) {
            int xx = xo + 16 * j;
            if (xx < 56) unpack_acc(img[xx * 16 + ci4] ^ xm, pk);
        }
        reduce_cat(red, gst + 1 * 512, pk, true, t);
        if (t < 32) {
            int which = t >> 4, c4 = t & 15;
            u32 v = img[(which ? 55 : 0) * 16 + c4] ^ xm;
            for (int b = 0; b < 4; b++)
                for (int k = 0; k < 8; k++)
                    if ((v >> (8 * b + k)) & 1)
                        atomicAdd(&gst[(5 + which) * 512 + (c4 * 4 + b) * 8 + k], 1);
        }
    }
    if (slab == 13) {  // Rbot (j=2) + corners 7,8
        u32 pk[8] = {0,0,0,0,0,0,0,0};
#pragma unroll
        for (int j = 0; j < 4; j++) {
            int xx = xo + 16 * j;
            if (xx < 56) unpack_acc(img[(size_t)55 * 1024 + xx * 16 + ci4] ^ xm, pk);
        }
        reduce_cat(red, gst + 2 * 512, pk, true, t);
        if (t < 32) {
            int which = t >> 4, c4 = t & 15;
            u32 v = img[(size_t)55 * 1024 + (which ? 55 : 0) * 16 + c4] ^ xm;
            for (int b = 0; b < 4; b++)
                for (int k = 0; k < 8; k++)
                    if ((v >> (8 * b + k)) & 1)
                        atomicAdd(&gst[(7 + which) * 512 + (c4 * 4 + b) * 8 + k], 1);
        }
    }
}

// ===== int8 3x3 conv via MFMA, rows looped per block (B-tile staged once) =====
template <int SECOND>
static __device__ void conv_rows(int b, int t, SMem* sm,
                                 const char* __restrict__ qin, const char* __restrict__ qw,
                                 const int* __restrict__ wsum, const char* __restrict__ qid,
                                 const float* __restrict__ gg, const float* __restrict__ bb,
                                 const float* __restrict__ mmp, const float* __restrict__ vvp,
                                 float sIn, float sW, float sx,
                                 float* __restrict__ outp, u32* rmaxp) {
    int w = t >> 6, lane = t & 63, mq = lane & 15, quad = lane >> 4;
    // stage B: 576 rows (tap,co) x 20 dw (64B data + 16B pad) — once per block
    const uint4* bq4 = (const uint4*)qw;
    for (int j4 = t; j4 < 2304; j4 += 256) {
        int row = j4 >> 2, rem = j4 & 3;
        *(uint4*)&sm->conv.lb[row * 20 + rem * 4] = bq4[j4];
    }
    // per-thread epilogue constants (co depends only on nt,mq)
    float alpha[4], beta[4]; int wofs[4];
#pragma unroll
    for (int nt = 0; nt < 4; nt++) {
        int co = nt * 16 + mq;
        float inv = gg[co] * rsqrtf(vvp[co] + 1e-5f);
        alpha[nt] = sIn * sW * inv;
        beta[nt]  = bb[co] - mmp[co] * inv;
        wofs[nt]  = SECOND ? (wsum[co] << 7) : 0;
    }
    float lmax = 0.f;
    const uint4* qin4 = (const uint4*)qin;
    for (int u = b; u < 896; u += NB) {
        int n = u / 56, y = u - n * 56;
        v4i acc[4] = {{0,0,0,0},{0,0,0,0},{0,0,0,0},{0,0,0,0}};
#pragma unroll
        for (int ky = 0; ky < 3; ky++) {
            __syncthreads();                         // protect lin from previous use
            for (int r4 = t; r4 < 264; r4 += 256) {  // 66 px (x=-1..64) x 4 uint4
                int px = r4 >> 2, rem = r4 & 3;
                *(uint4*)&sm->conv.lin[px * 20 + rem * 4] =
                    qin4[(size_t)(1 + n * ROWS_PI + y + ky) * 256 - 4 + r4];
            }
            __syncthreads();
#pragma unroll
            for (int kx = 0; kx < 3; kx++) {
                int px = w * 16 + mq + kx;
                v4i a = *(const v4i*)&sm->conv.lin[px * 20 + quad * 4];
                int tap = ky * 3 + kx;
#pragma unroll
                for (int nt = 0; nt < 4; nt++) {
                    int co = nt * 16 + mq;
                    v4i bf = *(const v4i*)&sm->conv.lb[(tap * 64 + co) * 20 + quad * 4];
                    acc[nt] = __builtin_amdgcn_mfma_i32_16x16x64_i8(a, bf, acc[nt], 0, 0, 0);
                }
            }
        }
        // epilogue
        size_t rowb = (size_t)u * 3584;
        const signed char* idrow = SECOND
            ? (const signed char*)(qid + (size_t)(2 + n * ROWS_PI + y) * PADROW) : nullptr;
#pragma unroll
        for (int nt = 0; nt < 4; nt++) {
            int co = nt * 16 + mq;
#pragma unroll
            for (int r = 0; r < 4; r++) {
                int xx = w * 16 + quad * 4 + r;
                if (xx < 56) {
                    float o = (float)(acc[nt][r] + wofs[nt]) * alpha[nt] + beta[nt];
                    if (SECOND) o += sx * (float)idrow[xx * 64 + co];
                    outp[rowb + xx * 64 + co] = o;
                    lmax = fmaxf(lmax, o);
                }
            }
        }
    }
    __syncthreads();
    sm->conv.red[t] = lmax; __syncthreads();
    for (int s = 128; s > 0; s >>= 1) {
        if (t < s) sm->conv.red[t] = fmaxf(sm->conv.red[t], sm->conv.red[t + s]);
        __syncthreads();
    }
    if (t == 0) atomicMax(rmaxp, __float_as_uint(sm->conv.red[0]));
}

// ===== the whole pipeline as ONE cooperative persistent kernel =====
__global__ __launch_bounds__(256, 2) void k_mega(
        const float* __restrict__ x,  const float* __restrict__ w1, const float* __restrict__ w2,
        const float* __restrict__ g1, const float* __restrict__ b1,
        const float* __restrict__ m1, const float* __restrict__ v1,
        const float* __restrict__ g2, const float* __restrict__ b2,
        const float* __restrict__ m2, const float* __restrict__ v2,
        char* __restrict__ ws, float* __restrict__ outp) {
    __shared__ SMem sm;
    const int b = blockIdx.x, t = threadIdx.x;
    char*  const qx    = ws + OFS_QX;
    char*  const q1    = ws + OFS_Q1;
    float* const o1    = (float*)(ws + OFS_O1);
    float* const o2    = (float*)(ws + OFS_O2);
    char*  const qw1   = ws + OFS_QW1;
    char*  const qw2   = ws + OFS_QW2;
    int*   const wb1   = (int*)(ws + OFS_WB1);
    int*   const wb2   = (int*)(ws + OFS_WB2);
    int*   const wsum  = (int*)(ws + OFS_WSUM);
    u32*   const rmax1 = (u32*)(ws + OFS_SCAL + 128);
    u32*   const rmax2 = (u32*)(ws + OFS_SCAL + 256);
    u32*   const bar   = (u32*)(ws + OFS_BAR);
    int*   const stx   = (int*)(ws + OFS_STX);
    int*   const stq   = (int*)(ws + OFS_STQ);
    float* const wsred = (float*)(ws + OFS_WSRED);

    // ---------- stage A: absmax partials (x: blocks 0..447, w1: 448..479, w2: 480..511) ----------
    {
        float mx = 0.f;
        if (b < 448) {
            const float4* p4 = (const float4*)x;
            for (int i = b * 256 + t; i < 802816; i += 448 * 256) {
                float4 v = p4[i];
                mx = fmaxf(mx, fmaxf(fmaxf(fabsf(v.x), fabsf(v.y)),
                                     fmaxf(fabsf(v.z), fabsf(v.w))));
            }
        } else {
            const float4* p4 = (const float4*)(b < 480 ? w1 : w2);
            for (int i = ((b - 448) & 31) * 256 + t; i < 9216; i += 32 * 256) {
                float4 v = p4[i];
                mx = fmaxf(mx, fmaxf(fmaxf(fabsf(v.x), fabsf(v.y)),
                                     fmaxf(fabsf(v.z), fabsf(v.w))));
            }
        }
        mx = block_redmax(mx, sm.amax.red, t);
        if (t == 0) wsred[b] = mx;
    }
    gsync(bar, 0);

    // ---------- stage B: scales (every block, locally) + quant_x + quant_w ----------
    float maxX, maxW1, maxW2;
    {
        float aX = wsred[t];
        if (t < 192) aX = fmaxf(aX, wsred[256 + t]);
        maxX  = block_redmax(aX, sm.amax.red, t);
        maxW1 = block_redmax(t < 32 ? wsred[448 + t] : 0.f, sm.amax.red, t);
        maxW2 = block_redmax(t < 32 ? wsred[480 + t] : 0.f, sm.amax.red, t);
    }
    {
        float sxq = maxX / 127.f;
        for (int u = b; u < 928; u += NB) {
            int n = u / 58, yy = u - n * 58;
            u32* row = (u32*)(qx + (size_t)(1 + n * ROWS_PI + yy) * PADROW);
            if (n == 0 && yy == 0) { u32* r0 = (u32*)qx; for (int j = t; j < 1024; j += 256) r0[j] = 0u; }
            if (yy == 0 || yy == 57) { for (int j = t; j < 1024; j += 256) row[j] = 0u; continue; }
            int y = yy - 1;
            __syncthreads();
            for (int idx = t; idx < 3584; idx += 256) {
                int c = idx / 56, xx = idx - c * 56;
                float v = x[(size_t)n * 200704 + (size_t)c * 3136 + y * 56 + xx];
                float q = rintf(v / sxq);
                q = fminf(fmaxf(q, -127.f), 127.f);
                sm.qx.lq[xx * 64 + c] = (char)(int)q;
            }
            __syncthreads();
            u32* lqd = (u32*)sm.qx.lq;
            for (int j = t; j < 1024; j += 256) row[j] = (j < 896) ? lqd[j] : 0u;
        }
        if (b >= NB - 18) {   // 18 blocks: quantize weights, bit-stats, wsum
            __syncthreads();
            int wu = b - (NB - 18);
            int wsel = wu / 9, kp = wu - wsel * 9;
            const float* w = wsel ? w2 : w1;
            char* qw = wsel ? qw2 : qw1;
            int* wb  = wsel ? wb2 : wb1;
            float s = (wsel ? maxW2 : maxW1) / 127.f;
            int co = t & 63, cg = t >> 6, ci0 = cg * 16;
            signed char qv[16];
            int qsum = 0;
#pragma unroll
            for (int i = 0; i < 16; i++) {
                int ci = ci0 + i;
                float v = w[((size_t)co * 64 + ci) * 9 + kp];
                float qf = rintf(v / s);
                qf = fminf(fmaxf(qf, -127.f), 127.f);
                int q = (int)qf;
                qv[i] = (signed char)q;
                qsum += q;
            }
            u32 pk[4];
#pragma unroll
            for (int d = 0; d < 4; d++)
                pk[d] = ((u32)(unsigned char)qv[d*4]) | ((u32)(unsigned char)qv[d*4+1] << 8)
                      | ((u32)(unsigned char)qv[d*4+2] << 16) | ((u32)(unsigned char)qv[d*4+3] << 24);
            *(uint4*)&qw[(size_t)(kp * 64 + co) * 64 + ci0] = *(uint4*)pk;
#pragma unroll
            for (int i = 0; i < 16; i++) {
                u32 uu = (u32)(unsigned char)qv[i];
#pragma unroll
                for (int k = 0; k < 8; k++) {
                    unsigned long long bal = __ballot((uu >> k) & 1);
                    if (co == 0) wb[((ci0 + i) * 8 + k) * 9 + kp] = __popcll(bal);
                }
            }
            if (wsel == 1) {
                sm.qw.wsl[t] = qsum; __syncthreads();
                if (t < 64)
                    atomicAdd(&wsum[t], sm.qw.wsl[t] + sm.qw.wsl[t + 64]
                                      + sm.qw.wsl[t + 128] + sm.qw.wsl[t + 192]);
            }
        }
    }
    gsync(bar, 1);

    // ---------- stage C: conv1 (+rmax1) and stats(qx) ----------
    conv_rows<0>(b, t, &sm, qx, qw1, nullptr, nullptr, g1, b1, m1, v1,
                 maxX / 127.f, maxW1 / 127.f, 0.f, o1, rmax1);
    if (b >= 288) stats_unit(&sm, qx, 0u, stx, b - 288, t);
    gsync(bar, 2);

    // ---------- stage D: quant_relu1 ----------
    float s1 = __uint_as_float(aloadu(rmax1)) / 255.f;
    for (int u = b; u < 928; u += NB) {
        int n = u / 58, yy = u - n * 58;
        u32* row = (u32*)(q1 + (size_t)(1 + n * ROWS_PI + yy) * PADROW);
        if (n == 0 && yy == 0) { u32* r0 = (u32*)q1; for (int j = t; j < 1024; j += 256) r0[j] = 0x80808080u; }
        if (yy == 0 || yy == 57) { for (int j = t; j < 1024; j += 256) row[j] = 0x80808080u; continue; }
        int y = yy - 1;
        char* rowb = (char*)row;
        const float* orow = o1 + (size_t)(n * 56 + y) * 3584;
        for (int idx = t; idx < 3584; idx += 256) {
            float vv = fmaxf(orow[idx], 0.f);
            float q = fminf(rintf(vv / s1), 255.f);
            rowb[idx] = (char)((int)q - 128);
        }
        for (int j = 896 + t; j < 1024; j += 256) row[j] = 0x80808080u;
    }
    gsync(bar, 3);

    // ---------- stage E: conv2 (+rmax2) and stats(q1) ----------
    conv_rows<1>(b, t, &sm, q1, qw2, wsum, qx, g2, b2, m2, v2,
                 s1, maxW2 / 127.f, maxX / 127.f, o2, rmax2);
    if (b >= 288) stats_unit(&sm, q1, 0x80u, stq, b - 288, t);
    gsync(bar, 4);

    // ---------- stage F: final quantize + NHWC->NCHW, and HM combine on last block ----------
    {
        float s2 = __uint_as_float(aloadu(rmax2)) / 255.f;
        for (int u = b; u < 896; u += NB) {
            int n = u / 56, y = u - n * 56;
            __syncthreads();
            const float* orow = o2 + (size_t)u * 3584;
            for (int idx = t; idx < 3584; idx += 256) {
                int co = idx & 63, xx = idx >> 6;
                float vv = fmaxf(orow[idx], 0.f);
                float q = fminf(rintf(vv / s2), 255.f);
                sm.fin.lt[co * 57 + xx] = q * s2;
            }
            __syncthreads();
            for (int idx = t; idx < 3584; idx += 256) {
                int co = idx / 56, xx = idx - co * 56;
                outp[(size_t)n * 200704 + (size_t)co * 3136 + y * 56 + xx] = sm.fin.lt[co * 57 + xx];
            }
        }
        if (b == NB - 1) {
            __syncthreads();
            long long act = 0, en = 0;
#pragma unroll
            for (int half = 0; half < 2; half++) {
                int tt = t + half * 256;   // tt = ci*8 + k
#pragma unroll
                for (int wsel = 0; wsel < 2; wsel++) {
                    const int* st = wsel ? stq : stx;
                    const int* wb = wsel ? wb2 : wb1;
                    long long s[9];
#pragma unroll
                    for (int j = 0; j < 9; j++) s[j] = aload(&st[j * 512 + tt]);
                    int wr[9];
#pragma unroll
                    for (int j = 0; j < 9; j++) wr[j] = aload(&wb[tt * 9 + j]);
                    long long wall = 0;
#pragma unroll
                    for (int j = 0; j < 9; j++) wall += wr[j];
                    long long wr0 = (long long)wr[0] + wr[1] + wr[2];
                    long long wr2 = (long long)wr[6] + wr[7] + wr[8];
                    long long wc0 = (long long)wr[0] + wr[3] + wr[6];
                    long long wc2 = (long long)wr[2] + wr[5] + wr[8];
                    en += s[0] * wall - s[1] * wr2 - s[2] * wr0 - s[3] * wc2 - s[4] * wc0
                        + s[5] * (long long)wr[8] + s[6] * (long long)wr[6]
                        + s[7] * (long long)wr[2] + s[8] * (long long)wr[0];
                    act += s[0];
                }
            }
            sm.hm.r1[t] = en; __syncthreads();
            for (int s = 128; s > 0; s >>= 1) { if (t < s) sm.hm.r1[t] += sm.hm.r1[t + s]; __syncthreads(); }
            long long etot = sm.hm.r1[0]; __syncthreads();
            sm.hm.r1[t] = act; __syncthreads();
            for (int s = 128; s > 0; s >>= 1) { if (t < s) sm.hm.r1[t] += sm.hm.r1[t + s]; __syncthreads(); }
            if (t == 0) {
                outp[OUTN]     = (float)sm.hm.r1[0];  // HM_act
                outp[OUTN + 1] = (float)etot;         // HM_energy
            }
        }
    }
}

extern "C" void kernel_launch(void* const* d_in, const int* in_sizes, int n_in,
                              void* d_out, int out_size, void* d_ws, size_t ws_size,
                              hipStream_t stream) {
    if (ws_size < WS_NEED) return;
    const float* x  = (const float*)d_in[0];
    const float* w1 = (const float*)d_in[1];
    const float* w2 = (const float*)d_in[2];
    const float* g1 = (const float*)d_in[3];
    const float* b1 = (const float*)d_in[4];
    const float* m1 = (const float*)d_in[5];
    const float* v1 = (const float*)d_in[6];
    const float* g2 = (const float*)d_in[7];
    const float* b2 = (const float*)d_in[8];
    const float* m2 = (const float*)d_in[9];
    const float* v2 = (const float*)d_in[10];
    char* ws = (char*)d_ws;
    float* outp = (float*)d_out;
    // zero atomic accumulators + rmax + grid-barrier counters (workspace is re-poisoned each iter)
    (void)hipMemsetAsync(ws + OFS_WSUM, 0, ZSPAN, stream);
    void* args[] = { (void*)&x, (void*)&w1, (void*)&w2,
                     (void*)&g1, (void*)&b1, (void*)&m1, (void*)&v1,
                     (void*)&g2, (void*)&b2, (void*)&m2, (void*)&v2,
                     (void*)&ws, (void*)&outp };
    (void)hipLaunchCooperativeKernel((const void*)k_mega, dim3(NB), dim3(256),
                                     args, 0, stream);
}

// Round 3
// 267.810 us; speedup vs baseline: 2.3412x; 2.3412x over previous
//
#include <hip/hip_runtime.h>

using u32 = unsigned int;
typedef int v4i __attribute__((ext_vector_type(4)));

// ===== geometry =====
constexpr int N_IMG   = 16;
constexpr int PADROW  = 4096;   // 64 px * 64 ch bytes
constexpr int ROWS_PI = 58;     // 56 real + top/bottom pad
constexpr int NB      = 512;    // cooperative grid: 2 blocks/CU, runtime-validated co-residency

// ===== workspace layout (bytes) =====
constexpr size_t OFS_QX   = 4096;
constexpr size_t SZ_QPAD  = (size_t)(1 + N_IMG * ROWS_PI) * PADROW;
constexpr size_t OFS_Q1   = OFS_QX + SZ_QPAD;
constexpr size_t OFS_O1   = OFS_Q1 + SZ_QPAD;
constexpr size_t SZ_OF    = (size_t)N_IMG * 56 * 56 * 64 * 4;
constexpr size_t OFS_O2   = OFS_O1 + SZ_OF;
constexpr size_t OFS_QW1  = OFS_O2 + SZ_OF;
constexpr size_t OFS_QW2  = OFS_QW1 + 36864;
constexpr size_t OFS_WB1  = OFS_QW2 + 36864;
constexpr size_t OFS_WB2  = OFS_WB1 + 18432;
constexpr size_t OFS_WSUM = OFS_WB2 + 18432;      // 64 ints (zeroed)
constexpr size_t OFS_SCAL = OFS_WSUM + 256;       // rmax1 @+128, rmax2 @+256 — own cachelines (zeroed)
constexpr size_t OFS_REL  = OFS_SCAL + 384;       // 16 release flags x 128B (zeroed)
constexpr size_t OFS_STX  = OFS_REL + 2048;       // 4608 ints (zeroed)
constexpr size_t OFS_STQ  = OFS_STX + 18432;      // 4608 ints (zeroed)
constexpr size_t OFS_FLAG = OFS_STQ + 18432;      // 512 arrival flags x 128B (zeroed)
constexpr size_t OFS_WSRED= OFS_FLAG + 65536;     // 512 floats absmax partials (written, not zeroed)
constexpr size_t WS_NEED  = OFS_WSRED + 2048;
constexpr size_t ZSPAN    = OFS_WSRED - OFS_WSUM; // one memset covers wsum..flags (~105 KB)
constexpr size_t OUTN     = (size_t)16 * 64 * 56 * 56;

// ===== shared memory union (max 52384 B -> 2 blocks/CU with margin) =====
union __align__(16) SMem {
    struct { u32 lb[11520]; u32 lin[1320]; float red[256]; } conv; // 46080+5280+1024
    struct { char lq[4096]; } qx;
    struct { u32 red[2048]; } st;
    struct { float lt[64 * 57]; } fin;
    struct { float red[256]; } amax;
    struct { int wsl[256]; } qw;
    struct { long long r1[256]; } hm;
};
static_assert(sizeof(SMem) <= 64 * 1024, "LDS budget");

// ===== helpers =====
static __device__ __forceinline__ int aload(const int* p) {
    return __hip_atomic_load((int*)p, __ATOMIC_RELAXED, __HIP_MEMORY_SCOPE_AGENT);
}
static __device__ __forceinline__ u32 aloadu(u32* p) {
    return __hip_atomic_load(p, __ATOMIC_RELAXED, __HIP_MEMORY_SCOPE_AGENT);
}

// ===== contention-free grid barrier =====
// Arrival: each block release-stores generation (idx+1) to its OWN 128B-padded flag
//          (512 parallel stores, no RMW, no shared cacheline).
// Check:   block 0's threads poll flags with RELAXED loads (no per-poll cache maintenance),
//          then release-store rel[idx].
// Wait:    blocks poll rel[idx] RELAXED; ONE acquire load per block invalidates local
//          caches before cross-XCD reads. rel/flags zeroed by the launch-time memset.
static __device__ __forceinline__ void gsync(u32* flags, u32* rel, int idx, int b, int t) {
    __syncthreads();
    if (t == 0)
        __hip_atomic_store(&flags[b * 32], (u32)(idx + 1), __ATOMIC_RELEASE, __HIP_MEMORY_SCOPE_AGENT);
    if (b == 0) {
#pragma unroll
        for (int h = 0; h < 2; h++) {
            int j = t + h * 256;
            int guard = 0;
            while (__hip_atomic_load(&flags[j * 32], __ATOMIC_RELAXED, __HIP_MEMORY_SCOPE_AGENT)
                   < (u32)(idx + 1)) {
                __builtin_amdgcn_s_sleep(1);
                if (++guard > (1 << 18)) break;   // ms-scale failsafe; never expected to trip
            }
        }
        __syncthreads();
        if (t == 0) {
            __hip_atomic_store(&rel[idx * 32], 1u, __ATOMIC_RELEASE, __HIP_MEMORY_SCOPE_AGENT);
            (void)__hip_atomic_load(&rel[idx * 32], __ATOMIC_ACQUIRE, __HIP_MEMORY_SCOPE_AGENT);
        }
    } else {
        if (t == 0) {
            int guard = 0;
            while (__hip_atomic_load(&rel[idx * 32], __ATOMIC_RELAXED, __HIP_MEMORY_SCOPE_AGENT) == 0u) {
                __builtin_amdgcn_s_sleep(1);
                if (++guard > (1 << 18)) break;
            }
            (void)__hip_atomic_load(&rel[idx * 32], __ATOMIC_ACQUIRE, __HIP_MEMORY_SCOPE_AGENT);
        }
    }
    __syncthreads();
}

static __device__ __forceinline__ float block_redmax(float v, float* red, int t) {
    red[t] = v; __syncthreads();
    for (int s = 128; s > 0; s >>= 1) {
        if (t < s) red[t] = fmaxf(red[t], red[t + s]);
        __syncthreads();
    }
    float r = red[0]; __syncthreads();
    return r;
}

// ===== bit-stats (identical math to the verified multi-kernel k_stats) =====
static __device__ __forceinline__ void unpack_acc(u32 v, u32 pk[8]) {
#pragma unroll
    for (int k = 0; k < 8; k++) pk[k] += (v >> k) & 0x01010101u;
}

static __device__ __forceinline__ void reduce_cat(u32* red, int* gdst, const u32 pk[8],
                                                  bool active, int t) {
#pragma unroll
    for (int k = 0; k < 8; k++) red[k * 256 + t] = active ? pk[k] : 0u;
    __syncthreads();
#pragma unroll
    for (int p = t; p < 512; p += 256) {
        int ci = p >> 3, k = p & 7, ci4 = ci >> 2, b = ci & 3;
        int sum = 0;
#pragma unroll
        for (int xo = 0; xo < 16; xo++)
            sum += (red[k * 256 + xo * 16 + ci4] >> (8 * b)) & 0xFF;
        if (sum) atomicAdd(&gdst[p], sum);
    }
    __syncthreads();
}

static __device__ void stats_unit(SMem* sm, const char* qpad, u32 xorm, int* gst, int s, int t) {
    __syncthreads();                      // LDS handoff from conv
    int n = s / 14, slab = s - n * 14;
    int ci4 = t & 15, xo = t >> 4;
    const u32* img = (const u32*)(qpad + (size_t)(2 + n * ROWS_PI) * PADROW);
    u32 xm = xorm * 0x01010101u;
    u32* red = sm->st.red;
    int y0 = slab * 4;
    {   // main total (j=0)
        u32 pk[8] = {0,0,0,0,0,0,0,0};
#pragma unroll
        for (int r = 0; r < 4; r++) {
            const u32* row = img + (size_t)(y0 + r) * 1024;
#pragma unroll
            for (int j = 0; j < 4; j++) {
                int xx = xo + 16 * j;
                if (xx < 56) unpack_acc(row[xx * 16 + ci4] ^ xm, pk);
            }
        }
        reduce_cat(red, gst + 0 * 512, pk, true, t);
    }
    {   // Cleft (j=3)
        u32 pk[8] = {0,0,0,0,0,0,0,0};
        bool act = (xo == 0);
        if (act)
#pragma unroll
            for (int r = 0; r < 4; r++)
                unpack_acc(img[(size_t)(y0 + r) * 1024 + ci4] ^ xm, pk);
        reduce_cat(red, gst + 3 * 512, pk, act, t);
    }
    {   // Cright (j=4)
        u32 pk[8] = {0,0,0,0,0,0,0,0};
        bool act = (xo == 7);
        if (act)
#pragma unroll
            for (int r = 0; r < 4; r++)
                unpack_acc(img[(size_t)(y0 + r) * 1024 + 55 * 16 + ci4] ^ xm, pk);
        reduce_cat(red, gst + 4 * 512, pk, act, t);
    }
    if (slab == 0) {   // Rtop (j=1) + corners 5,6
        u32 pk[8] = {0,0,0,0,0,0,0,0};
#pragma unroll
        for (int j = 0; j < 4; j++) {
            int xx = xo + 16 * j;
            if (xx < 56) unpack_acc(img[xx * 16 + ci4] ^ xm, pk);
        }
        reduce_cat(red, gst + 1 * 512, pk, true, t);
        if (t < 32) {
            int which = t >> 4, c4 = t & 15;
            u32 v = img[(which ? 55 : 0) * 16 + c4] ^ xm;
            for (int b = 0; b < 4; b++)
                for (int k = 0; k < 8; k++)
                    if ((v >> (8 * b + k)) & 1)
                        atomicAdd(&gst[(5 + which) * 512 + (c4 * 4 + b) * 8 + k], 1);
        }
    }
    if (slab == 13) {  // Rbot (j=2) + corners 7,8
        u32 pk[8] = {0,0,0,0,0,0,0,0};
#pragma unroll
        for (int j = 0; j < 4; j++) {
            int xx = xo + 16 * j;
            if (xx < 56) unpack_acc(img[(size_t)55 * 1024 + xx * 16 + ci4] ^ xm, pk);
        }
        reduce_cat(red, gst + 2 * 512, pk, true, t);
        if (t < 32) {
            int which = t >> 4, c4 = t & 15;
            u32 v = img[(size_t)55 * 1024 + (which ? 55 : 0) * 16 + c4] ^ xm;
            for (int b = 0; b < 4; b++)
                for (int k = 0; k < 8; k++)
                    if ((v >> (8 * b + k)) & 1)
                        atomicAdd(&gst[(7 + which) * 512 + (c4 * 4 + b) * 8 + k], 1);
        }
    }
}

// ===== int8 3x3 conv via MFMA, rows looped per block (B-tile staged once) =====
template <int SECOND>
static __device__ void conv_rows(int b, int t, SMem* sm,
                                 const char* __restrict__ qin, const char* __restrict__ qw,
                                 const int* __restrict__ wsum, const char* __restrict__ qid,
                                 const float* __restrict__ gg, const float* __restrict__ bb,
                                 const float* __restrict__ mmp, const float* __restrict__ vvp,
                                 float sIn, float sW, float sx,
                                 float* __restrict__ outp, u32* rmaxp) {
    int w = t >> 6, lane = t & 63, mq = lane & 15, quad = lane >> 4;
    // stage B: 576 rows (tap,co) x 20 dw (64B data + 16B pad) — once per block
    const uint4* bq4 = (const uint4*)qw;
    for (int j4 = t; j4 < 2304; j4 += 256) {
        int row = j4 >> 2, rem = j4 & 3;
        *(uint4*)&sm->conv.lb[row * 20 + rem * 4] = bq4[j4];
    }
    // per-thread epilogue constants (co depends only on nt,mq)
    float alpha[4], beta[4]; int wofs[4];
#pragma unroll
    for (int nt = 0; nt < 4; nt++) {
        int co = nt * 16 + mq;
        float inv = gg[co] * rsqrtf(vvp[co] + 1e-5f);
        alpha[nt] = sIn * sW * inv;
        beta[nt]  = bb[co] - mmp[co] * inv;
        wofs[nt]  = SECOND ? (wsum[co] << 7) : 0;
    }
    float lmax = 0.f;
    const uint4* qin4 = (const uint4*)qin;
    for (int u = b; u < 896; u += NB) {
        int n = u / 56, y = u - n * 56;
        v4i acc[4] = {{0,0,0,0},{0,0,0,0},{0,0,0,0},{0,0,0,0}};
#pragma unroll
        for (int ky = 0; ky < 3; ky++) {
            __syncthreads();                         // protect lin from previous use
            for (int r4 = t; r4 < 264; r4 += 256) {  // 66 px (x=-1..64) x 4 uint4
                int px = r4 >> 2, rem = r4 & 3;
                *(uint4*)&sm->conv.lin[px * 20 + rem * 4] =
                    qin4[(size_t)(1 + n * ROWS_PI + y + ky) * 256 - 4 + r4];
            }
            __syncthreads();
#pragma unroll
            for (int kx = 0; kx < 3; kx++) {
                int px = w * 16 + mq + kx;
                v4i a = *(const v4i*)&sm->conv.lin[px * 20 + quad * 4];
                int tap = ky * 3 + kx;
#pragma unroll
                for (int nt = 0; nt < 4; nt++) {
                    int co = nt * 16 + mq;
                    v4i bf = *(const v4i*)&sm->conv.lb[(tap * 64 + co) * 20 + quad * 4];
                    acc[nt] = __builtin_amdgcn_mfma_i32_16x16x64_i8(a, bf, acc[nt], 0, 0, 0);
                }
            }
        }
        // epilogue
        size_t rowb = (size_t)u * 3584;
        const signed char* idrow = SECOND
            ? (const signed char*)(qid + (size_t)(2 + n * ROWS_PI + y) * PADROW) : nullptr;
#pragma unroll
        for (int nt = 0; nt < 4; nt++) {
            int co = nt * 16 + mq;
#pragma unroll
            for (int r = 0; r < 4; r++) {
                int xx = w * 16 + quad * 4 + r;
                if (xx < 56) {
                    float o = (float)(acc[nt][r] + wofs[nt]) * alpha[nt] + beta[nt];
                    if (SECOND) o += sx * (float)idrow[xx * 64 + co];
                    outp[rowb + xx * 64 + co] = o;
                    lmax = fmaxf(lmax, o);
                }
            }
        }
    }
    __syncthreads();
    sm->conv.red[t] = lmax; __syncthreads();
    for (int s = 128; s > 0; s >>= 1) {
        if (t < s) sm->conv.red[t] = fmaxf(sm->conv.red[t], sm->conv.red[t + s]);
        __syncthreads();
    }
    if (t == 0) atomicMax(rmaxp, __float_as_uint(sm->conv.red[0]));
}

// ===== the whole pipeline as ONE cooperative persistent kernel =====
__global__ __launch_bounds__(256, 2) void k_mega(
        const float* __restrict__ x,  const float* __restrict__ w1, const float* __restrict__ w2,
        const float* __restrict__ g1, const float* __restrict__ b1,
        const float* __restrict__ m1, const float* __restrict__ v1,
        const float* __restrict__ g2, const float* __restrict__ b2,
        const float* __restrict__ m2, const float* __restrict__ v2,
        char* __restrict__ ws, float* __restrict__ outp) {
    __shared__ SMem sm;
    const int b = blockIdx.x, t = threadIdx.x;
    char*  const qx    = ws + OFS_QX;
    char*  const q1    = ws + OFS_Q1;
    float* const o1    = (float*)(ws + OFS_O1);
    float* const o2    = (float*)(ws + OFS_O2);
    char*  const qw1   = ws + OFS_QW1;
    char*  const qw2   = ws + OFS_QW2;
    int*   const wb1   = (int*)(ws + OFS_WB1);
    int*   const wb2   = (int*)(ws + OFS_WB2);
    int*   const wsum  = (int*)(ws + OFS_WSUM);
    u32*   const rmax1 = (u32*)(ws + OFS_SCAL + 128);
    u32*   const rmax2 = (u32*)(ws + OFS_SCAL + 256);
    u32*   const rel   = (u32*)(ws + OFS_REL);
    u32*   const flags = (u32*)(ws + OFS_FLAG);
    int*   const stx   = (int*)(ws + OFS_STX);
    int*   const stq   = (int*)(ws + OFS_STQ);
    float* const wsred = (float*)(ws + OFS_WSRED);

    // ---------- stage A: absmax partials (x: blocks 0..447, w1: 448..479, w2: 480..511) ----------
    {
        float mx = 0.f;
        if (b < 448) {
            const float4* p4 = (const float4*)x;
            for (int i = b * 256 + t; i < 802816; i += 448 * 256) {
                float4 v = p4[i];
                mx = fmaxf(mx, fmaxf(fmaxf(fabsf(v.x), fabsf(v.y)),
                                     fmaxf(fabsf(v.z), fabsf(v.w))));
            }
        } else {
            const float4* p4 = (const float4*)(b < 480 ? w1 : w2);
            for (int i = ((b - 448) & 31) * 256 + t; i < 9216; i += 32 * 256) {
                float4 v = p4[i];
                mx = fmaxf(mx, fmaxf(fmaxf(fabsf(v.x), fabsf(v.y)),
                                     fmaxf(fabsf(v.z), fabsf(v.w))));
            }
        }
        mx = block_redmax(mx, sm.amax.red, t);
        if (t == 0) wsred[b] = mx;
    }
    gsync(flags, rel, 0, b, t);

    // ---------- stage B: scales (every block, locally) + quant_x + quant_w ----------
    float maxX, maxW1, maxW2;
    {
        float aX = wsred[t];
        if (t < 192) aX = fmaxf(aX, wsred[256 + t]);
        maxX  = block_redmax(aX, sm.amax.red, t);
        maxW1 = block_redmax(t < 32 ? wsred[448 + t] : 0.f, sm.amax.red, t);
        maxW2 = block_redmax(t < 32 ? wsred[480 + t] : 0.f, sm.amax.red, t);
    }
    {
        float sxq = maxX / 127.f;
        for (int u = b; u < 928; u += NB) {
            int n = u / 58, yy = u - n * 58;
            u32* row = (u32*)(qx + (size_t)(1 + n * ROWS_PI + yy) * PADROW);
            if (n == 0 && yy == 0) { u32* r0 = (u32*)qx; for (int j = t; j < 1024; j += 256) r0[j] = 0u; }
            if (yy == 0 || yy == 57) { for (int j = t; j < 1024; j += 256) row[j] = 0u; continue; }
            int y = yy - 1;
            __syncthreads();
            for (int idx = t; idx < 3584; idx += 256) {
                int c = idx / 56, xx = idx - c * 56;
                float v = x[(size_t)n * 200704 + (size_t)c * 3136 + y * 56 + xx];
                float q = rintf(v / sxq);
                q = fminf(fmaxf(q, -127.f), 127.f);
                sm.qx.lq[xx * 64 + c] = (char)(int)q;
            }
            __syncthreads();
            u32* lqd = (u32*)sm.qx.lq;
            for (int j = t; j < 1024; j += 256) row[j] = (j < 896) ? lqd[j] : 0u;
        }
        if (b >= NB - 18) {   // 18 blocks: quantize weights, bit-stats, wsum
            __syncthreads();
            int wu = b - (NB - 18);
            int wsel = wu / 9, kp = wu - wsel * 9;
            const float* w = wsel ? w2 : w1;
            char* qw = wsel ? qw2 : qw1;
            int* wb  = wsel ? wb2 : wb1;
            float s = (wsel ? maxW2 : maxW1) / 127.f;
            int co = t & 63, cg = t >> 6, ci0 = cg * 16;
            signed char qv[16];
            int qsum = 0;
#pragma unroll
            for (int i = 0; i < 16; i++) {
                int ci = ci0 + i;
                float v = w[((size_t)co * 64 + ci) * 9 + kp];
                float qf = rintf(v / s);
                qf = fminf(fmaxf(qf, -127.f), 127.f);
                int q = (int)qf;
                qv[i] = (signed char)q;
                qsum += q;
            }
            u32 pk[4];
#pragma unroll
            for (int d = 0; d < 4; d++)
                pk[d] = ((u32)(unsigned char)qv[d*4]) | ((u32)(unsigned char)qv[d*4+1] << 8)
                      | ((u32)(unsigned char)qv[d*4+2] << 16) | ((u32)(unsigned char)qv[d*4+3] << 24);
            *(uint4*)&qw[(size_t)(kp * 64 + co) * 64 + ci0] = *(uint4*)pk;
#pragma unroll
            for (int i = 0; i < 16; i++) {
                u32 uu = (u32)(unsigned char)qv[i];
#pragma unroll
                for (int k = 0; k < 8; k++) {
                    unsigned long long bal = __ballot((uu >> k) & 1);
                    if (co == 0) wb[((ci0 + i) * 8 + k) * 9 + kp] = __popcll(bal);
                }
            }
            if (wsel == 1) {
                sm.qw.wsl[t] = qsum; __syncthreads();
                if (t < 64)
                    atomicAdd(&wsum[t], sm.qw.wsl[t] + sm.qw.wsl[t + 64]
                                      + sm.qw.wsl[t + 128] + sm.qw.wsl[t + 192]);
            }
        }
    }
    gsync(flags, rel, 1, b, t);

    // ---------- stage C: conv1 (+rmax1) and stats(qx) ----------
    conv_rows<0>(b, t, &sm, qx, qw1, nullptr, nullptr, g1, b1, m1, v1,
                 maxX / 127.f, maxW1 / 127.f, 0.f, o1, rmax1);
    if (b >= 288) stats_unit(&sm, qx, 0u, stx, b - 288, t);
    gsync(flags, rel, 2, b, t);

    // ---------- stage D: quant_relu1 ----------
    float s1 = __uint_as_float(aloadu(rmax1)) / 255.f;
    for (int u = b; u < 928; u += NB) {
        int n = u / 58, yy = u - n * 58;
        u32* row = (u32*)(q1 + (size_t)(1 + n * ROWS_PI + yy) * PADROW);
        if (n == 0 && yy == 0) { u32* r0 = (u32*)q1; for (int j = t; j < 1024; j += 256) r0[j] = 0x80808080u; }
        if (yy == 0 || yy == 57) { for (int j = t; j < 1024; j += 256) row[j] = 0x80808080u; continue; }
        int y = yy - 1;
        char* rowb = (char*)row;
        const float* orow = o1 + (size_t)(n * 56 + y) * 3584;
        for (int idx = t; idx < 3584; idx += 256) {
            float vv = fmaxf(orow[idx], 0.f);
            float q = fminf(rintf(vv / s1), 255.f);
            rowb[idx] = (char)((int)q - 128);
        }
        for (int j = 896 + t; j < 1024; j += 256) row[j] = 0x80808080u;
    }
    gsync(flags, rel, 3, b, t);

    // ---------- stage E: conv2 (+rmax2) and stats(q1) ----------
    conv_rows<1>(b, t, &sm, q1, qw2, wsum, qx, g2, b2, m2, v2,
                 s1, maxW2 / 127.f, maxX / 127.f, o2, rmax2);
    if (b >= 288) stats_unit(&sm, q1, 0x80u, stq, b - 288, t);
    gsync(flags, rel, 4, b, t);

    // ---------- stage F: final quantize + NHWC->NCHW, and HM combine on last block ----------
    {
        float s2 = __uint_as_float(aloadu(rmax2)) / 255.f;
        for (int u = b; u < 896; u += NB) {
            int n = u / 56, y = u - n * 56;
            __syncthreads();
            const float* orow = o2 + (size_t)u * 3584;
            for (int idx = t; idx < 3584; idx += 256) {
                int co = idx & 63, xx = idx >> 6;
                float vv = fmaxf(orow[idx], 0.f);
                float q = fminf(rintf(vv / s2), 255.f);
                sm.fin.lt[co * 57 + xx] = q * s2;
            }
            __syncthreads();
            for (int idx = t; idx < 3584; idx += 256) {
                int co = idx / 56, xx = idx - co * 56;
                outp[(size_t)n * 200704 + (size_t)co * 3136 + y * 56 + xx] = sm.fin.lt[co * 57 + xx];
            }
        }
        if (b == NB - 1) {
            __syncthreads();
            long long act = 0, en = 0;
#pragma unroll
            for (int half = 0; half < 2; half++) {
                int tt = t + half * 256;   // tt = ci*8 + k
#pragma unroll
                for (int wsel = 0; wsel < 2; wsel++) {
                    const int* st = wsel ? stq : stx;
                    const int* wb = wsel ? wb2 : wb1;
                    long long s[9];
#pragma unroll
                    for (int j = 0; j < 9; j++) s[j] = aload(&st[j * 512 + tt]);
                    int wr[9];
#pragma unroll
                    for (int j = 0; j < 9; j++) wr[j] = aload(&wb[tt * 9 + j]);
                    long long wall = 0;
#pragma unroll
                    for (int j = 0; j < 9; j++) wall += wr[j];
                    long long wr0 = (long long)wr[0] + wr[1] + wr[2];
                    long long wr2 = (long long)wr[6] + wr[7] + wr[8];
                    long long wc0 = (long long)wr[0] + wr[3] + wr[6];
                    long long wc2 = (long long)wr[2] + wr[5] + wr[8];
                    en += s[0] * wall - s[1] * wr2 - s[2] * wr0 - s[3] * wc2 - s[4] * wc0
                        + s[5] * (long long)wr[8] + s[6] * (long long)wr[6]
                        + s[7] * (long long)wr[2] + s[8] * (long long)wr[0];
                    act += s[0];
                }
            }
            sm.hm.r1[t] = en; __syncthreads();
            for (int s = 128; s > 0; s >>= 1) { if (t < s) sm.hm.r1[t] += sm.hm.r1[t + s]; __syncthreads(); }
            long long etot = sm.hm.r1[0]; __syncthreads();
            sm.hm.r1[t] = act; __syncthreads();
            for (int s = 128; s > 0; s >>= 1) { if (t < s) sm.hm.r1[t] += sm.hm.r1[t + s]; __syncthreads(); }
            if (t == 0) {
                outp[OUTN]     = (float)sm.hm.r1[0];  // HM_act
                outp[OUTN + 1] = (float)etot;         // HM_energy
            }
        }
    }
}

extern "C" void kernel_launch(void* const* d_in, const int* in_sizes, int n_in,
                              void* d_out, int out_size, void* d_ws, size_t ws_size,
                              hipStream_t stream) {
    if (ws_size < WS_NEED) return;
    const float* x  = (const float*)d_in[0];
    const float* w1 = (const float*)d_in[1];
    const float* w2 = (const float*)d_in[2];
    const float* g1 = (const float*)d_in[3];
    const float* b1 = (const float*)d_in[4];
    const float* m1 = (const float*)d_in[5];
    const float* v1 = (const float*)d_in[6];
    const float* g2 = (const float*)d_in[7];
    const float* b2 = (const float*)d_in[8];
    const float* m2 = (const float*)d_in[9];
    const float* v2 = (const float*)d_in[10];
    char* ws = (char*)d_ws;
    float* outp = (float*)d_out;
    // zero atomic accumulators + rmax + barrier flags/releases (workspace re-poisoned each iter)
    (void)hipMemsetAsync(ws + OFS_WSUM, 0, ZSPAN, stream);
    void* args[] = { (void*)&x, (void*)&w1, (void*)&w2,
                     (void*)&g1, (void*)&b1, (void*)&m1, (void*)&v1,
                     (void*)&g2, (void*)&b2, (void*)&m2, (void*)&v2,
                     (void*)&ws, (void*)&outp };
    (void)hipLaunchCooperativeKernel((const void*)k_mega, dim3(NB), dim3(256),
                                     args, 0, stream);
}